// Round 2
// baseline (227.796 us; speedup 1.0000x reference)
//
#include <hip/hip_runtime.h>

// B=16, T=1024, N=1024, D=256, WIN=64
// outputs (flat): R (B,T,2D) = [A@V, Q]   : 8388608 f32
//                 alignments (B,N,T) = A^T: 16777216 f32
//                 max_att (B,T)           : 16384 f32
// Out-of-window softmax entries are exactly 0.0f, so each block writes its
// full (N x 16t) alignment column-strip: zeros outside [prev, prev+WIN),
// probabilities inside. No memset needed; zero-fill overlaps compute and
// every store is a full 64B cache line (16 floats, t0 multiple of 16).

#define BB 16
#define TT 1024
#define NN 1024
#define DD 256
#define WIN 64
#define TBLK 16   // queries per block

#define R_ELEMS   (16u*1024u*512u)        // 8388608
#define ALN_ELEMS (16u*1024u*1024u)       // 16777216

__global__ __launch_bounds__(256) void attn_kernel(
    const float* __restrict__ Q, const float* __restrict__ K,
    const float* __restrict__ V, const int* __restrict__ prev_in,
    float* __restrict__ out)
{
    __shared__ float p_a[WIN][TBLK + 1];   // [j][t_local]  (stride 17: conflict-free)
    __shared__ float p_t[TBLK][WIN + 4];   // [t_local][j]  (stride 68: float4-aligned rows)

    float* Rout   = out;
    float* aligns = out + R_ELEMS;
    float* maxatt = out + R_ELEMS + ALN_ELEMS;

    const int tid  = threadIdx.x;
    const int lane = tid & 63;
    const int w    = tid >> 6;            // wave 0..3
    const int b    = blockIdx.x >> 6;     // 64 blocks per batch
    const int t0   = (blockIdx.x & 63) * TBLK;
    const int prev = prev_in[b];

    // ---- Phase 1: QK^T. Wave w: queries t0+w*4+{0..3}; lane = window col j.
    const float*  qb = Q + ((size_t)b * TT + t0 + w * 4) * DD;
    const float4* K4 = (const float4*)(K + ((size_t)b * NN + prev + lane) * DD);

    float acc[4] = {0.f, 0.f, 0.f, 0.f};
    for (int d4 = 0; d4 < DD / 4; ++d4) {
        float4 k = K4[d4];
        #pragma unroll
        for (int t = 0; t < 4; ++t) {
            float4 q = ((const float4*)(qb + t * DD))[d4];   // wave-broadcast load
            acc[t] = fmaf(q.x, k.x, fmaf(q.y, k.y, fmaf(q.z, k.z, fmaf(q.w, k.w, acc[t]))));
        }
    }

    // ---- Phase 2: softmax + argmax per query; stash p in LDS (both layouts).
    #pragma unroll
    for (int t = 0; t < 4; ++t) {
        float v = acc[t] * 0.0625f;       // 1/sqrt(256)

        float m = v;
        #pragma unroll
        for (int off = 32; off; off >>= 1) m = fmaxf(m, __shfl_xor(m, off));

        float e = expf(v - m);
        float s = e;
        #pragma unroll
        for (int off = 32; off; off >>= 1) s += __shfl_xor(s, off);

        float p = e / s;
        const int tt = w * 4 + t;
        p_a[lane][tt] = p;
        p_t[tt][lane] = p;

        // argmax over logits (== argmax over A), first-index tiebreak
        float av = v; int ai = lane;
        #pragma unroll
        for (int off = 32; off; off >>= 1) {
            float ov = __shfl_xor(av, off);
            int   oi = __shfl_xor(ai, off);
            if (ov > av || (ov == av && oi < ai)) { av = ov; ai = oi; }
        }
        if (lane == 0) maxatt[(size_t)b * TT + t0 + tt] = (float)(prev + ai);
    }
    __syncthreads();

    // ---- Phase 3: alignments column strip [b, 0..N, t0..t0+16) — zeros + p.
    {
        const int rsub = tid >> 2;        // 0..63: row within 64-row group
        const int cg   = tid & 3;         // float4 column group
        float* abase = aligns + (size_t)b * NN * TT + t0 + cg * 4;
        #pragma unroll
        for (int it = 0; it < NN / 64; ++it) {
            int n  = it * 64 + rsub;
            int iw = n - prev;
            float4 val = make_float4(0.f, 0.f, 0.f, 0.f);
            if ((unsigned)iw < WIN) {
                val.x = p_a[iw][cg * 4 + 0];
                val.y = p_a[iw][cg * 4 + 1];
                val.z = p_a[iw][cg * 4 + 2];
                val.w = p_a[iw][cg * 4 + 3];
            }
            *(float4*)(abase + (size_t)n * TT) = val;
        }
    }

    // ---- Phase 4: PV + R write. Thread = (t_local, d-chunk).
    {
        const int tl = tid >> 4;          // 0..15
        const int dc0 = tid & 15;
        const float4* V4 = (const float4*)(V + ((size_t)b * NN + prev) * DD);
        const float4* Q4 = (const float4*)(Q + ((size_t)b * TT + t0 + tl) * DD);
        float4* R4 = (float4*)(Rout + ((size_t)b * TT + t0 + tl) * (2 * DD));

        #pragma unroll
        for (int pass = 0; pass < 4; ++pass) {
            const int dc = pass * 16 + dc0;
            float4 o = make_float4(0.f, 0.f, 0.f, 0.f);
            #pragma unroll 4
            for (int j4 = 0; j4 < WIN / 4; ++j4) {
                float4 p4 = *(const float4*)&p_t[tl][j4 * 4];
                float4 v0 = V4[(size_t)(j4 * 4 + 0) * (DD / 4) + dc];
                float4 v1 = V4[(size_t)(j4 * 4 + 1) * (DD / 4) + dc];
                float4 v2 = V4[(size_t)(j4 * 4 + 2) * (DD / 4) + dc];
                float4 v3 = V4[(size_t)(j4 * 4 + 3) * (DD / 4) + dc];
                o.x = fmaf(p4.x, v0.x, fmaf(p4.y, v1.x, fmaf(p4.z, v2.x, fmaf(p4.w, v3.x, o.x))));
                o.y = fmaf(p4.x, v0.y, fmaf(p4.y, v1.y, fmaf(p4.z, v2.y, fmaf(p4.w, v3.y, o.y))));
                o.z = fmaf(p4.x, v0.z, fmaf(p4.y, v1.z, fmaf(p4.z, v2.z, fmaf(p4.w, v3.z, o.z))));
                o.w = fmaf(p4.x, v0.w, fmaf(p4.y, v1.w, fmaf(p4.z, v2.w, fmaf(p4.w, v3.w, o.w))));
            }
            R4[dc] = o;                   // attention output
            R4[DD / 4 + dc] = Q4[dc];     // Q copy
        }
    }
}

extern "C" void kernel_launch(void* const* d_in, const int* in_sizes, int n_in,
                              void* d_out, int out_size, void* d_ws, size_t ws_size,
                              hipStream_t stream) {
    const float* Q = (const float*)d_in[0];
    const float* K = (const float*)d_in[1];
    const float* V = (const float*)d_in[2];
    const int* prev = (const int*)d_in[3];
    float* out = (float*)d_out;

    // 64 blocks per batch, 16 queries per block: 1024 blocks x 256 threads.
    attn_kernel<<<BB * TT / TBLK, 256, 0, stream>>>(Q, K, V, prev, out);
}